// Round 3
// baseline (2497.314 us; speedup 1.0000x reference)
//
#include <hip/hip_runtime.h>
#include <stdint.h>

#define NN 8192
#define DD 64

// =====================================================================
// K1: k_pre — 64-row tile: transpose x -> xT (if ws allows) + squared norms.
// sq chain is scalar ascending-d fmaf; MUST match the k_cand dot chain so
// that d_ii == 0 exactly (faiss self-neighbour semantics).
// =====================================================================
__global__ __launch_bounds__(256) void k_pre(const float* __restrict__ x, float* __restrict__ xT,
                                             float* __restrict__ sq, int do_tr){
  __shared__ float tile[64*65]; // +1 pad breaks bank conflicts on transposed reads
  const int tid = threadIdx.x;
  const int b = blockIdx.x;
  for (int k = 0; k < 4; ++k){
    const int idx4 = tid + k*256;            // float4 index within 64x64 tile
    const float4 v = ((const float4*)(x + (size_t)b*4096))[idx4];
    const int row = idx4 >> 4, d0 = (idx4 & 15) * 4;
    tile[row*65 + d0 + 0] = v.x;
    tile[row*65 + d0 + 1] = v.y;
    tile[row*65 + d0 + 2] = v.z;
    tile[row*65 + d0 + 3] = v.w;
  }
  __syncthreads();
  if (do_tr){
    const int jj = tid & 15;   // j-quad
    const int dq = tid >> 4;   // 0..15
    for (int k = 0; k < 4; ++k){
      const int d = dq + 16*k;
      float4 o;
      o.x = tile[(jj*4+0)*65 + d];
      o.y = tile[(jj*4+1)*65 + d];
      o.z = tile[(jj*4+2)*65 + d];
      o.w = tile[(jj*4+3)*65 + d];
      ((float4*)xT)[(size_t)d*2048 + b*16 + jj] = o;
    }
  }
  if (tid < 64){
    float acc = 0.f;
    const float* rp = tile + tid*65;
    for (int d = 0; d < 64; ++d) acc = fmaf(rp[d], rp[d], acc);
    sq[b*64 + tid] = acc;
  }
}

// =====================================================================
// K2: k_cand — per 8 i-rows: (1) dists to a contiguous 1024-j window,
// bisection-select the 32nd smallest (+1ulp) as an upper bound on the
// 50th-NN distance (P[fail] ~ hypergeom tail ~1e-15; E[cands]=256,
// P[>512] ~ 1e-40); (2) full 8192-j pass collecting candidates under the
// bound; (3) exact 512-wide bitonic -> top-50 exp-sum (identical lane
// summation tree as round 2) + 16-NN ids.
// =====================================================================
template<bool XT>
__device__ __forceinline__ void dists_1024(const float* __restrict__ x, const float* __restrict__ xT,
                                           const float* __restrict__ xi, int jbase, int tid,
                                           float acc[8][4]){
#pragma unroll
  for (int r = 0; r < 8; ++r)
#pragma unroll
    for (int q = 0; q < 4; ++q) acc[r][q] = 0.f;
  const int j0 = jbase + tid*4;
  for (int dq = 0; dq < 16; ++dq){
    float4 vj[4];
    if (XT){
#pragma unroll
      for (int s = 0; s < 4; ++s)
        vj[s] = ((const float4*)xT)[(size_t)(dq*4+s)*2048 + (j0 >> 2)];
    } else {
#pragma unroll
      for (int s = 0; s < 4; ++s){
        const int d = dq*4 + s;
        vj[s].x = x[(size_t)(j0+0)*64 + d];
        vj[s].y = x[(size_t)(j0+1)*64 + d];
        vj[s].z = x[(size_t)(j0+2)*64 + d];
        vj[s].w = x[(size_t)(j0+3)*64 + d];
      }
    }
#pragma unroll
    for (int r = 0; r < 8; ++r){
      const float4 wv = ((const float4*)(xi + r*64))[dq];
      // ascending-d chain per (r,q): s = 0,1,2,3  (matches k_pre sq chain)
      acc[r][0] = fmaf(vj[0].x, wv.x, acc[r][0]);
      acc[r][1] = fmaf(vj[0].y, wv.x, acc[r][1]);
      acc[r][2] = fmaf(vj[0].z, wv.x, acc[r][2]);
      acc[r][3] = fmaf(vj[0].w, wv.x, acc[r][3]);
      acc[r][0] = fmaf(vj[1].x, wv.y, acc[r][0]);
      acc[r][1] = fmaf(vj[1].y, wv.y, acc[r][1]);
      acc[r][2] = fmaf(vj[1].z, wv.y, acc[r][2]);
      acc[r][3] = fmaf(vj[1].w, wv.y, acc[r][3]);
      acc[r][0] = fmaf(vj[2].x, wv.z, acc[r][0]);
      acc[r][1] = fmaf(vj[2].y, wv.z, acc[r][1]);
      acc[r][2] = fmaf(vj[2].z, wv.z, acc[r][2]);
      acc[r][3] = fmaf(vj[2].w, wv.z, acc[r][3]);
      acc[r][0] = fmaf(vj[3].x, wv.w, acc[r][0]);
      acc[r][1] = fmaf(vj[3].y, wv.w, acc[r][1]);
      acc[r][2] = fmaf(vj[3].z, wv.w, acc[r][2]);
      acc[r][3] = fmaf(vj[3].w, wv.w, acc[r][3]);
    }
  }
}

template<bool XT>
__global__ __launch_bounds__(256) void k_cand(const float* __restrict__ x, const float* __restrict__ xT,
                                              const float* __restrict__ sq,
                                              float* __restrict__ res, unsigned short* __restrict__ nn16){
  __shared__ float xi[8*64];
  __shared__ float sqi_s[8];
  __shared__ float tubs[8];
  __shared__ __align__(16) unsigned long long cand[8*512]; // 32KB; aliased as samp f32[8*1024]
  __shared__ unsigned ccnt[8];
  float* samp = (float*)cand;
  const int tid = threadIdx.x;
  const int i0 = blockIdx.x * 8;
  for (int t = tid; t < 8*64; t += 256) xi[t] = x[(size_t)i0*64 + t];
  if (tid < 8){ sqi_s[tid] = sq[i0+tid]; ccnt[tid] = 0u; }
  __syncthreads();
  float sqir[8];
#pragma unroll
  for (int r = 0; r < 8; ++r) sqir[r] = sqi_s[r];

  // ---- phase 1: sampled window ----
  const int w0 = (blockIdx.x * 1024) & 8191;
  {
    float acc[8][4];
    dists_1024<XT>(x, xT, xi, w0, tid, acc);
    float sqj[4];
#pragma unroll
    for (int q = 0; q < 4; ++q) sqj[q] = sq[w0 + tid*4 + q];
#pragma unroll
    for (int r = 0; r < 8; ++r)
#pragma unroll
      for (int q = 0; q < 4; ++q)
        samp[r*1024 + tid*4 + q] = (sqir[r] + sqj[q]) - 2.f*acc[r][q];
  }
  __syncthreads();

  // ---- bisection select: Tub[r] = 32nd smallest window dist + 1ulp ----
  {
    const int wv = tid >> 6, lane = tid & 63;
    for (int rr = 0; rr < 2; ++rr){
      const int r = wv + rr*4;
      float v[16];
#pragma unroll
      for (int k2 = 0; k2 < 16; ++k2) v[k2] = samp[r*1024 + lane + 64*k2];
      unsigned lo = 0u, hi = 0x7F800001u;
      while (hi - lo > 1u){
        const unsigned mid = (lo + hi) >> 1;
        const float pf = __uint_as_float(mid);
        int c = 0;
#pragma unroll
        for (int k2 = 0; k2 < 16; ++k2) c += (v[k2] < pf) ? 1 : 0;
#pragma unroll
        for (int off = 32; off; off >>= 1) c += __shfl_xor(c, off);
        if (c >= 32) hi = mid; else lo = mid;
      }
      if (lane == 0) tubs[r] = __uint_as_float(hi);
    }
  }
  __syncthreads();
  float tubr[8];
#pragma unroll
  for (int r = 0; r < 8; ++r) tubr[r] = tubs[r];
  for (int t = tid; t < 8*512; t += 256) cand[t] = ~0ULL;
  __syncthreads();

  // ---- phase 2: full sweep + filter ----
  for (int pass = 0; pass < 8; ++pass){
    const int jb = pass*1024;
    float acc[8][4];
    dists_1024<XT>(x, xT, xi, jb, tid, acc);
    const int j0 = jb + tid*4;
    float sqj[4];
#pragma unroll
    for (int q = 0; q < 4; ++q) sqj[q] = sq[j0 + q];
#pragma unroll
    for (int r = 0; r < 8; ++r){
#pragma unroll
      for (int q = 0; q < 4; ++q){
        const float dist = (sqir[r] + sqj[q]) - 2.f*acc[r][q];
        if (dist < tubr[r]){
          const unsigned pos = atomicAdd(&ccnt[r], 1u);
          if (pos < 512u){
            unsigned u = __float_as_uint(dist);
            u = ((int)u < 0) ? ~u : (u | 0x80000000u);
            cand[r*512 + pos] = (((unsigned long long)u) << 13) | (unsigned)(j0 + q);
          }
        }
      }
    }
  }
  __syncthreads();

  // ---- phase 3: exact bitonic over 512 candidates per row ----
  for (int k = 2; k <= 512; k <<= 1){
    for (int jj2 = k >> 1; jj2 > 0; jj2 >>= 1){
      const int mm = tid; // 256 CE per row, 256 threads
      const int i = ((mm & ~(jj2-1)) << 1) | (mm & (jj2-1));
      const int p = i | jj2;
      const bool up2 = ((i & k) == 0);
#pragma unroll
      for (int r = 0; r < 8; ++r){
        unsigned long long a = cand[r*512+i], bb = cand[r*512+p];
        if ((a > bb) == up2){ cand[r*512+i] = bb; cand[r*512+p] = a; }
      }
      __syncthreads();
    }
  }

  // ---- outputs: identical summation structure to round 2 ----
  const int wv2 = tid >> 6, lane2 = tid & 63;
  for (int rr = 0; rr < 2; ++rr){
    const int r = wv2*2 + rr;
    const unsigned long long kk = cand[r*512 + lane2];
    float e = 0.f;
    if (lane2 < 50){
      unsigned u2 = (unsigned)(kk >> 13);
      u2 = (u2 & 0x80000000u) ? (u2 & 0x7FFFFFFFu) : ~u2;
      e = expf(-__uint_as_float(u2) / 30.f);
    }
#pragma unroll
    for (int off = 32; off; off >>= 1) e += __shfl_down(e, off);
    if (lane2 == 0) res[i0+r] = e / 1500.f;
    if (lane2 < 16) nn16[(size_t)(i0+r)*16 + lane2] = (unsigned short)(kk & 8191ULL);
  }
}

// =====================================================================
// K3: k_sortu — max(res) + stable argsort (64KB LDS bitonic) + rank inverse
// + grouped-transposed upward-neighbour lists for k_uf. Single block.
// =====================================================================
__global__ __launch_bounds__(1024) void k_sortu(const float* __restrict__ res,
                                                const unsigned short* __restrict__ nn16,
                                                float* __restrict__ dens_s,
                                                unsigned short* __restrict__ ups_t){
  __shared__ unsigned long long keys[NN]; // 64KB
  __shared__ unsigned short rankv[NN];    // 16KB
  __shared__ float red[1024];
  const int tid = threadIdx.x;
  float m = 0.f;
  for (int t = tid; t < NN; t += 1024) m = fmaxf(m, res[t]);
  red[tid] = m; __syncthreads();
  for (int o = 512; o; o >>= 1){ if (tid < o) red[tid] = fmaxf(red[tid], red[tid+o]); __syncthreads(); }
  const float mr = red[0];
  for (int t = tid; t < NN; t += 1024){
    const float dnv = res[t] / mr;
    keys[t] = (((unsigned long long)__float_as_uint(dnv)) << 13) | (unsigned)t;
  }
  __syncthreads();
  for (int k = 2; k <= NN; k <<= 1){
    for (int j = k >> 1; j > 0; j >>= 1){
      for (int m2 = tid; m2 < NN/2; m2 += 1024){
        const int i = ((m2 & ~(j-1)) << 1) | (m2 & (j-1));
        const int p = i | j;
        const bool up = ((i & k) == 0);
        unsigned long long a = keys[i], b = keys[p];
        if ((a > b) == up){ keys[i] = b; keys[p] = a; }
      }
      __syncthreads();
    }
  }
  for (int t = tid; t < NN; t += 1024){
    const unsigned long long kk = keys[t];
    dens_s[t] = __uint_as_float((unsigned)(kk >> 13));
    rankv[(unsigned)(kk & 8191ULL)] = (unsigned short)t;
  }
  __syncthreads();
  // upward lists: sorted desc, grouped-transposed: group g covers p=4g+3-t,
  // ups_t[g*64 + t*16 + k] = k-th largest upward rank, 0-padded.
  for (int pp = 0; pp < 8; ++pp){
    const int p = tid + pp*1024;
    const unsigned orig = (unsigned)(keys[p] & 8191ULL);
    unsigned short outv[16];
    int cnt = 0;
    for (int k = 0; k < 16; ++k){
      const unsigned r = rankv[nn16[(size_t)orig*16 + k]];
      if ((int)r > p){
        int q = cnt++;
        while (q > 0 && outv[q-1] < (unsigned short)r){ outv[q] = outv[q-1]; --q; }
        outv[q] = (unsigned short)r;
      }
    }
    for (int k = cnt; k < 16; ++k) outv[k] = 0;
    unsigned short* dst = ups_t + (size_t)(p >> 2)*64 + (3 - (p & 3))*16;
    uint4 a, b;
    a.x = (unsigned)outv[0] | ((unsigned)outv[1] << 16);
    a.y = (unsigned)outv[2] | ((unsigned)outv[3] << 16);
    a.z = (unsigned)outv[4] | ((unsigned)outv[5] << 16);
    a.w = (unsigned)outv[6] | ((unsigned)outv[7] << 16);
    b.x = (unsigned)outv[8] | ((unsigned)outv[9] << 16);
    b.y = (unsigned)outv[10] | ((unsigned)outv[11] << 16);
    b.z = (unsigned)outv[12] | ((unsigned)outv[13] << 16);
    b.w = (unsigned)outv[14] | ((unsigned)outv[15] << 16);
    ((uint4*)dst)[0] = a;
    ((uint4*)dst)[1] = b;
  }
}

// =====================================================================
// K4: k_uf — single-wave union-find sweep (eager-root invariant, find = 1
// LDS read). Deaths collected as ordered (dead->live) pairs; ONE range-
// limited compare-select sweep per group (gated: skipped when the dying
// component provably has no members and no in-group chain). Fused loss tail
// emulates round-2 k_loss's exact fp reduction order.
// =====================================================================
__global__ __launch_bounds__(64) void k_uf(const unsigned short* __restrict__ ups_t,
                                           const float* __restrict__ dens_g,
                                           float* __restrict__ out){
  __shared__ __align__(16) unsigned short par[NN];   // 16KB
  __shared__ __align__(16) unsigned short death[NN]; // 16KB
  __shared__ __align__(16) unsigned short hasm[NN];  // 16KB
  __shared__ __align__(16) float dens[NN];           // 32KB
  __shared__ unsigned pairbuf[64];
  __shared__ float psum[1024];
  const int lane = threadIdx.x;
  for (int t = lane; t < NN/2; t += 64){
    ((unsigned*)par)[t]   = ((unsigned)(2*t+1) << 16) | (unsigned)(2*t);
    ((unsigned*)death)[t] = 0xFFFFFFFFu;
    ((unsigned*)hasm)[t]  = 0u;
  }
  for (int t = lane; t < NN/4; t += 64)
    ((float4*)dens)[t] = ((const float4*)dens_g)[t];
  __syncthreads();

  unsigned short nb[6];
#pragma unroll
  for (int k = 0; k < 6; ++k) nb[k] = ups_t[(size_t)(2047-k)*64 + lane];

  for (int g = 2047; g >= 0; --g){
    const unsigned u = nb[0];
#pragma unroll
    for (int k = 0; k < 5; ++k) nb[k] = nb[k+1];
    if (g >= 6) nb[5] = ups_t[(size_t)(g-6)*64 + lane];
    const unsigned long long ball = __ballot(u != 0u);
    if (ball == 0ULL) continue;
    int root = par[u];          // eager invariant: one read == find
    int cnt = 0;
    bool needsweep = false;
    const int p3 = 4*g + 3;
#pragma unroll
    for (int t = 0; t < 4; ++t){
      if (((ball >> (16*t)) & 0xFFFFULL) == 0ULL) continue; // peak: par[p]=p stays
      const int p = p3 - t;
      const int r_up = __builtin_amdgcn_readlane(root, 16*t); // lane 16t holds u_max
      if (lane == 16*t){ par[p] = (unsigned short)r_up; hasm[r_up] = 1; }
      const bool mine = (u != 0u) && ((lane >> 4) == t);
      const bool cond = mine && (root != r_up);
      const unsigned long long dmask = __ballot(cond);
      if (dmask != 0ULL){
        const int hm = cond ? (int)hasm[root] : 0;
        needsweep = needsweep | (__ballot(cond && (hm != 0)) != 0ULL);
        const unsigned pos = (unsigned)cnt + (unsigned)__popcll(dmask & ((1ULL << lane) - 1ULL));
        if (cond){
          pairbuf[pos] = ((unsigned)root << 16) | (unsigned)r_up;
          death[root] = (unsigned short)p;   // threshold=1.0 => always merges
          par[root]   = (unsigned short)r_up;
          hasm[r_up]  = 1;
        }
        cnt += (int)__popcll(dmask);
        root = par[root];        // refresh in-register roots (one hop to live)
      }
      root = (u == (unsigned)p) ? r_up : root; // in-group attach fixup
    }
    if (cnt >= 2) needsweep = true;  // in-group dead->dead chains need repair
    if (needsweep){
      // ordered-pair compare-select sweep over par[(4g & ~511) .. NN)
      uint4* p4 = (uint4*)par;
      const int c0 = ((4*g) & ~511) >> 3;
      for (int c = c0 + lane; c < NN/8; c += 64){
        uint4 v = p4[c];
        for (int k = 0; k < cnt; ++k){
          const unsigned pr = pairbuf[k];
          const unsigned d = pr >> 16, s = pr & 0xFFFFu;
          unsigned a, b;
          a = v.x & 0xFFFFu; b = v.x >> 16; a = (a==d)?s:a; b = (b==d)?s:b; v.x = a | (b<<16);
          a = v.y & 0xFFFFu; b = v.y >> 16; a = (a==d)?s:a; b = (b==d)?s:b; v.y = a | (b<<16);
          a = v.z & 0xFFFFu; b = v.z >> 16; a = (a==d)?s:a; b = (b==d)?s:b; v.z = a | (b<<16);
          a = v.w & 0xFFFFu; b = v.w >> 16; a = (a==d)?s:a; b = (b==d)?s:b; v.w = a | (b<<16);
        }
        p4[c] = v;
      }
    }
  }
  __syncthreads();

  // ---- fused loss (bit-identical emulation of round-2 k_loss) ----
  float accv[16];
#pragma unroll
  for (int v2 = 0; v2 < 16; ++v2) accv[v2] = 0.f;
  for (int v2 = 0; v2 < 16; ++v2){
    const int t = lane + 64*v2;
    for (int e = t; e < NN; e += 1024){
      const int dr = death[e];
      if (dr != 0xFFFF) accv[v2] += dens[e] - dens[dr];
    }
  }
  for (int v2 = 0; v2 < 16; ++v2) psum[lane + 64*v2] = accv[v2];
  for (int o = 512; o; o >>= 1){
    for (int t = lane; t < o; t += 64) psum[t] += psum[t + o];
  }
  const float S = psum[0];
  unsigned long long sel10[10];
  unsigned long long last = ~0ULL;
#pragma unroll
  for (int t10 = 0; t10 < 10; ++t10){
    unsigned long long km = 0ULL;
    for (int e = lane; e < NN; e += 64){
      const int dr = death[e];
      if (dr != 0xFFFF){
        const float pers = dens[e] - dens[dr];
        const unsigned long long k = (((unsigned long long)__float_as_uint(pers)) << 13) | (unsigned)e;
        if (k < last && k > km) km = k;
      }
    }
#pragma unroll
    for (int off = 32; off; off >>= 1){
      const unsigned long long o =
        (((unsigned long long)(unsigned)__shfl_xor((int)(km >> 32), off)) << 32)
        | (unsigned long long)(unsigned)__shfl_xor((int)(km & 0xFFFFFFFFu), off);
      km = (o > km) ? o : km;
    }
    sel10[t10] = km;
    last = km;
  }
  if (lane == 0){
    float top = 0.f;
#pragma unroll
    for (int t10 = 0; t10 < 10; ++t10)
      if (sel10[t10]) top += __uint_as_float((unsigned)(sel10[t10] >> 13));
    float strong = 0.f, dest0 = 0.f, dest1 = 0.f;
    if (sel10[0]){
      const unsigned e0 = (unsigned)(sel10[0] & 8191ULL);
      dest0 = dens[e0]; dest1 = dens[death[e0]];
    }
#pragma unroll
    for (int t10 = 1; t10 < 10; ++t10){
      if (!sel10[t10]) continue;
      const unsigned e = (unsigned)(sel10[t10] & 8191ULL);
      const float a = dens[e] - dest0;
      const float b = dens[death[e]] - dest1;
      strong += sqrtf(a*a + b*b);
    }
    const float weak = (S - top) / 1.41421356237309515f;
    out[0] = weak + strong;
  }
}

// =====================================================================
// launch — 4 dispatches (was 8): tests the per-dispatch-overhead theory.
// =====================================================================
extern "C" void kernel_launch(void* const* d_in, const int* in_sizes, int n_in,
                              void* d_out, int out_size, void* d_ws, size_t ws_size,
                              hipStream_t stream){
  const float* x = (const float*)d_in[0];
  char* w = (char*)d_ws;
  float*          sq     = (float*)(w + 0);        // 32KB
  float*          res    = (float*)(w + 32768);    // 32KB
  float*          dens_s = (float*)(w + 65536);    // 32KB
  unsigned short* nn16   = (unsigned short*)(w + 98304);   // 256KB
  unsigned short* ups_t  = (unsigned short*)(w + 360448);  // 256KB
  float*          xT     = (float*)(w + 622592);   // 2MB (optional)
  const int use_xt = (ws_size >= (size_t)(622592 + NN*DD*4)) ? 1 : 0;

  k_pre<<<128, 256, 0, stream>>>(x, xT, sq, use_xt);
  if (use_xt) k_cand<true ><<<1024, 256, 0, stream>>>(x, xT, sq, res, nn16);
  else        k_cand<false><<<1024, 256, 0, stream>>>(x, xT, sq, res, nn16);
  k_sortu<<<1, 1024, 0, stream>>>(res, nn16, dens_s, ups_t);
  k_uf<<<1, 64, 0, stream>>>(ups_t, dens_s, (float*)d_out);
}

// Round 4
// 2471.750 us; speedup vs baseline: 1.0103x; 1.0103x over previous
//
#include <hip/hip_runtime.h>
#include <stdint.h>

#define NN 8192
#define DD 64

// =====================================================================
// K1: k_pre — 64-row tile: transpose x -> xT (if ws allows) + squared norms.
// sq chain is scalar ascending-d fmaf; MUST match the k_cand dot chain so
// that d_ii == 0 exactly (faiss self-neighbour semantics).
// =====================================================================
__global__ __launch_bounds__(256) void k_pre(const float* __restrict__ x, float* __restrict__ xT,
                                             float* __restrict__ sq, int do_tr){
  __shared__ float tile[64*65]; // +1 pad breaks bank conflicts on transposed reads
  const int tid = threadIdx.x;
  const int b = blockIdx.x;
  for (int k = 0; k < 4; ++k){
    const int idx4 = tid + k*256;            // float4 index within 64x64 tile
    const float4 v = ((const float4*)(x + (size_t)b*4096))[idx4];
    const int row = idx4 >> 4, d0 = (idx4 & 15) * 4;
    tile[row*65 + d0 + 0] = v.x;
    tile[row*65 + d0 + 1] = v.y;
    tile[row*65 + d0 + 2] = v.z;
    tile[row*65 + d0 + 3] = v.w;
  }
  __syncthreads();
  if (do_tr){
    const int jj = tid & 15;   // j-quad
    const int dq = tid >> 4;   // 0..15
    for (int k = 0; k < 4; ++k){
      const int d = dq + 16*k;
      float4 o;
      o.x = tile[(jj*4+0)*65 + d];
      o.y = tile[(jj*4+1)*65 + d];
      o.z = tile[(jj*4+2)*65 + d];
      o.w = tile[(jj*4+3)*65 + d];
      ((float4*)xT)[(size_t)d*2048 + b*16 + jj] = o;
    }
  }
  if (tid < 64){
    float acc = 0.f;
    const float* rp = tile + tid*65;
    for (int d = 0; d < 64; ++d) acc = fmaf(rp[d], rp[d], acc);
    sq[b*64 + tid] = acc;
  }
}

// =====================================================================
// K2: k_cand — per 8 i-rows: (1) dists to a contiguous 1024-j window,
// bisection-select the 32nd smallest (+1ulp) as an upper bound on the
// 50th-NN distance (P[fail] ~ hypergeom tail ~1e-15; E[cands]=256,
// P[>512] ~ 1e-40); (2) full 8192-j pass collecting candidates under the
// bound; (3) exact 512-wide bitonic -> top-50 exp-sum (identical lane
// summation tree as round 2) + 16-NN ids.
// =====================================================================
template<bool XT>
__device__ __forceinline__ void dists_1024(const float* __restrict__ x, const float* __restrict__ xT,
                                           const float* __restrict__ xi, int jbase, int tid,
                                           float acc[8][4]){
#pragma unroll
  for (int r = 0; r < 8; ++r)
#pragma unroll
    for (int q = 0; q < 4; ++q) acc[r][q] = 0.f;
  const int j0 = jbase + tid*4;
  for (int dq = 0; dq < 16; ++dq){
    float4 vj[4];
    if (XT){
#pragma unroll
      for (int s = 0; s < 4; ++s)
        vj[s] = ((const float4*)xT)[(size_t)(dq*4+s)*2048 + (j0 >> 2)];
    } else {
#pragma unroll
      for (int s = 0; s < 4; ++s){
        const int d = dq*4 + s;
        vj[s].x = x[(size_t)(j0+0)*64 + d];
        vj[s].y = x[(size_t)(j0+1)*64 + d];
        vj[s].z = x[(size_t)(j0+2)*64 + d];
        vj[s].w = x[(size_t)(j0+3)*64 + d];
      }
    }
#pragma unroll
    for (int r = 0; r < 8; ++r){
      const float4 wv = ((const float4*)(xi + r*64))[dq];
      acc[r][0] = fmaf(vj[0].x, wv.x, acc[r][0]);
      acc[r][1] = fmaf(vj[0].y, wv.x, acc[r][1]);
      acc[r][2] = fmaf(vj[0].z, wv.x, acc[r][2]);
      acc[r][3] = fmaf(vj[0].w, wv.x, acc[r][3]);
      acc[r][0] = fmaf(vj[1].x, wv.y, acc[r][0]);
      acc[r][1] = fmaf(vj[1].y, wv.y, acc[r][1]);
      acc[r][2] = fmaf(vj[1].z, wv.y, acc[r][2]);
      acc[r][3] = fmaf(vj[1].w, wv.y, acc[r][3]);
      acc[r][0] = fmaf(vj[2].x, wv.z, acc[r][0]);
      acc[r][1] = fmaf(vj[2].y, wv.z, acc[r][1]);
      acc[r][2] = fmaf(vj[2].z, wv.z, acc[r][2]);
      acc[r][3] = fmaf(vj[2].w, wv.z, acc[r][3]);
      acc[r][0] = fmaf(vj[3].x, wv.w, acc[r][0]);
      acc[r][1] = fmaf(vj[3].y, wv.w, acc[r][1]);
      acc[r][2] = fmaf(vj[3].z, wv.w, acc[r][2]);
      acc[r][3] = fmaf(vj[3].w, wv.w, acc[r][3]);
    }
  }
}

template<bool XT>
__global__ __launch_bounds__(256) void k_cand(const float* __restrict__ x, const float* __restrict__ xT,
                                              const float* __restrict__ sq,
                                              float* __restrict__ res, unsigned short* __restrict__ nn16){
  __shared__ float xi[8*64];
  __shared__ float sqi_s[8];
  __shared__ float tubs[8];
  __shared__ __align__(16) unsigned long long cand[8*512]; // 32KB; aliased as samp f32[8*1024]
  __shared__ unsigned ccnt[8];
  float* samp = (float*)cand;
  const int tid = threadIdx.x;
  const int i0 = blockIdx.x * 8;
  for (int t = tid; t < 8*64; t += 256) xi[t] = x[(size_t)i0*64 + t];
  if (tid < 8){ sqi_s[tid] = sq[i0+tid]; ccnt[tid] = 0u; }
  __syncthreads();
  float sqir[8];
#pragma unroll
  for (int r = 0; r < 8; ++r) sqir[r] = sqi_s[r];

  // ---- phase 1: sampled window ----
  const int w0 = (blockIdx.x * 1024) & 8191;
  {
    float acc[8][4];
    dists_1024<XT>(x, xT, xi, w0, tid, acc);
    float sqj[4];
#pragma unroll
    for (int q = 0; q < 4; ++q) sqj[q] = sq[w0 + tid*4 + q];
#pragma unroll
    for (int r = 0; r < 8; ++r)
#pragma unroll
      for (int q = 0; q < 4; ++q)
        samp[r*1024 + tid*4 + q] = (sqir[r] + sqj[q]) - 2.f*acc[r][q];
  }
  __syncthreads();

  // ---- bisection select: Tub[r] = 32nd smallest window dist + 1ulp ----
  {
    const int wv = tid >> 6, lane = tid & 63;
    for (int rr = 0; rr < 2; ++rr){
      const int r = wv + rr*4;
      float v[16];
#pragma unroll
      for (int k2 = 0; k2 < 16; ++k2) v[k2] = samp[r*1024 + lane + 64*k2];
      unsigned lo = 0u, hi = 0x7F800001u;
      while (hi - lo > 1u){
        const unsigned mid = (lo + hi) >> 1;
        const float pf = __uint_as_float(mid);
        int c = 0;
#pragma unroll
        for (int k2 = 0; k2 < 16; ++k2) c += (v[k2] < pf) ? 1 : 0;
#pragma unroll
        for (int off = 32; off; off >>= 1) c += __shfl_xor(c, off);
        if (c >= 32) hi = mid; else lo = mid;
      }
      if (lane == 0) tubs[r] = __uint_as_float(hi);
    }
  }
  __syncthreads();
  float tubr[8];
#pragma unroll
  for (int r = 0; r < 8; ++r) tubr[r] = tubs[r];
  for (int t = tid; t < 8*512; t += 256) cand[t] = ~0ULL;
  __syncthreads();

  // ---- phase 2: full sweep + filter ----
  for (int pass = 0; pass < 8; ++pass){
    const int jb = pass*1024;
    float acc[8][4];
    dists_1024<XT>(x, xT, xi, jb, tid, acc);
    const int j0 = jb + tid*4;
    float sqj[4];
#pragma unroll
    for (int q = 0; q < 4; ++q) sqj[q] = sq[j0 + q];
#pragma unroll
    for (int r = 0; r < 8; ++r){
#pragma unroll
      for (int q = 0; q < 4; ++q){
        const float dist = (sqir[r] + sqj[q]) - 2.f*acc[r][q];
        if (dist < tubr[r]){
          const unsigned pos = atomicAdd(&ccnt[r], 1u);
          if (pos < 512u){
            unsigned u = __float_as_uint(dist);
            u = ((int)u < 0) ? ~u : (u | 0x80000000u);
            cand[r*512 + pos] = (((unsigned long long)u) << 13) | (unsigned)(j0 + q);
          }
        }
      }
    }
  }
  __syncthreads();

  // ---- phase 3: exact bitonic over 512 candidates per row ----
  for (int k = 2; k <= 512; k <<= 1){
    for (int jj2 = k >> 1; jj2 > 0; jj2 >>= 1){
      const int mm = tid;
      const int i = ((mm & ~(jj2-1)) << 1) | (mm & (jj2-1));
      const int p = i | jj2;
      const bool up2 = ((i & k) == 0);
#pragma unroll
      for (int r = 0; r < 8; ++r){
        unsigned long long a = cand[r*512+i], bb = cand[r*512+p];
        if ((a > bb) == up2){ cand[r*512+i] = bb; cand[r*512+p] = a; }
      }
      __syncthreads();
    }
  }

  // ---- outputs: identical summation structure to round 2 ----
  const int wv2 = tid >> 6, lane2 = tid & 63;
  for (int rr = 0; rr < 2; ++rr){
    const int r = wv2*2 + rr;
    const unsigned long long kk = cand[r*512 + lane2];
    float e = 0.f;
    if (lane2 < 50){
      unsigned u2 = (unsigned)(kk >> 13);
      u2 = (u2 & 0x80000000u) ? (u2 & 0x7FFFFFFFu) : ~u2;
      e = expf(-__uint_as_float(u2) / 30.f);
    }
#pragma unroll
    for (int off = 32; off; off >>= 1) e += __shfl_down(e, off);
    if (lane2 == 0) res[i0+r] = e / 1500.f;
    if (lane2 < 16) nn16[(size_t)(i0+r)*16 + lane2] = (unsigned short)(kk & 8191ULL);
  }
}

// =====================================================================
// K3: k_sortu — max(res) + stable argsort (64KB LDS bitonic) + rank inverse
// + grouped-transposed upward-neighbour lists for k_uf. Single block.
// =====================================================================
__global__ __launch_bounds__(1024) void k_sortu(const float* __restrict__ res,
                                                const unsigned short* __restrict__ nn16,
                                                float* __restrict__ dens_s,
                                                unsigned short* __restrict__ ups_t){
  __shared__ unsigned long long keys[NN]; // 64KB
  __shared__ unsigned short rankv[NN];    // 16KB
  __shared__ float red[1024];
  const int tid = threadIdx.x;
  float m = 0.f;
  for (int t = tid; t < NN; t += 1024) m = fmaxf(m, res[t]);
  red[tid] = m; __syncthreads();
  for (int o = 512; o; o >>= 1){ if (tid < o) red[tid] = fmaxf(red[tid], red[tid+o]); __syncthreads(); }
  const float mr = red[0];
  for (int t = tid; t < NN; t += 1024){
    const float dnv = res[t] / mr;
    keys[t] = (((unsigned long long)__float_as_uint(dnv)) << 13) | (unsigned)t;
  }
  __syncthreads();
  for (int k = 2; k <= NN; k <<= 1){
    for (int j = k >> 1; j > 0; j >>= 1){
      for (int m2 = tid; m2 < NN/2; m2 += 1024){
        const int i = ((m2 & ~(j-1)) << 1) | (m2 & (j-1));
        const int p = i | j;
        const bool up = ((i & k) == 0);
        unsigned long long a = keys[i], b = keys[p];
        if ((a > b) == up){ keys[i] = b; keys[p] = a; }
      }
      __syncthreads();
    }
  }
  for (int t = tid; t < NN; t += 1024){
    const unsigned long long kk = keys[t];
    dens_s[t] = __uint_as_float((unsigned)(kk >> 13));
    rankv[(unsigned)(kk & 8191ULL)] = (unsigned short)t;
  }
  __syncthreads();
  // upward lists: sorted desc, grouped-transposed: group g covers p=4g+3-t,
  // ups_t[g*64 + t*16 + k] = k-th largest upward rank, 0-padded.
  for (int pp = 0; pp < 8; ++pp){
    const int p = tid + pp*1024;
    const unsigned orig = (unsigned)(keys[p] & 8191ULL);
    unsigned short outv[16];
    int cnt = 0;
    for (int k = 0; k < 16; ++k){
      const unsigned r = rankv[nn16[(size_t)orig*16 + k]];
      if ((int)r > p){
        int q = cnt++;
        while (q > 0 && outv[q-1] < (unsigned short)r){ outv[q] = outv[q-1]; --q; }
        outv[q] = (unsigned short)r;
      }
    }
    for (int k = cnt; k < 16; ++k) outv[k] = 0;
    unsigned short* dst = ups_t + (size_t)(p >> 2)*64 + (3 - (p & 3))*16;
    uint4 a, b;
    a.x = (unsigned)outv[0] | ((unsigned)outv[1] << 16);
    a.y = (unsigned)outv[2] | ((unsigned)outv[3] << 16);
    a.z = (unsigned)outv[4] | ((unsigned)outv[5] << 16);
    a.w = (unsigned)outv[6] | ((unsigned)outv[7] << 16);
    b.x = (unsigned)outv[8] | ((unsigned)outv[9] << 16);
    b.y = (unsigned)outv[10] | ((unsigned)outv[11] << 16);
    b.z = (unsigned)outv[12] | ((unsigned)outv[13] << 16);
    b.w = (unsigned)outv[14] | ((unsigned)outv[15] << 16);
    ((uint4*)dst)[0] = a;
    ((uint4*)dst)[1] = b;
  }
}

// =====================================================================
// K4: k_uf — single-wave union-find, 2-hop invariant, NO sweeps.
// Invariants: (a) par[x] for processed member x = root at x's last update
// (may since have died); (b) par[d] for every DEAD root d = current live
// root (maintained by deadlist scan at each death). => find(u)=par[par[u]].
// Both hops software-pipelined across 4-iteration groups; staleness fixed
// by register compare-selects:
//   - in-group deaths (root==d -> r_up) and attachments (u==p -> r_up)
//   - previous group's (d->r) pairs replayed at group top (covers neighbors
//     attached in prev group whose root died later within that group).
// Fused loss tail = bit-exact emulation of round-2 k_loss.
// =====================================================================
__global__ __launch_bounds__(64) void k_uf(const unsigned short* __restrict__ ups_t,
                                           const float* __restrict__ dens_g,
                                           float* __restrict__ out){
  __shared__ __align__(16) unsigned short par[NN];       // 16KB
  __shared__ __align__(16) unsigned short death[NN];     // 16KB
  __shared__ __align__(16) unsigned short deadlist[4096];// 8KB
  __shared__ unsigned gpair[64];                         // (d<<16)|r pairs of current group
  __shared__ __align__(16) float dens[NN];               // 32KB
  __shared__ float psum[1024];                           // 4KB
  const int lane = threadIdx.x;
  for (int t = lane; t < NN/2; t += 64){
    ((unsigned*)par)[t]   = ((unsigned)(2*t+1) << 16) | (unsigned)(2*t);
    ((unsigned*)death)[t] = 0xFFFFFFFFu;
  }
  for (int t = lane; t < NN/4; t += 64)
    ((float4*)dens)[t] = ((const float4*)dens_g)[t];
  __syncthreads();

  // pipeline warmup: par is identity before any processing
  unsigned u_cur = ups_t[(size_t)2047*64 + lane];  // u for group 2047
  unsigned u_n1  = ups_t[(size_t)2046*64 + lane];  // u for group 2046
  unsigned root  = u_cur;                          // h2 for 2047 (identity par)
  unsigned h1n   = u_n1;                           // h1 for 2046 (identity par)
  unsigned q[6];                                   // q[k] = u for group g-2-k
#pragma unroll
  for (int k = 0; k < 6; ++k) q[k] = ups_t[(size_t)(2045-k)*64 + lane];
  int nd = 0;      // deadlist length (uniform)
  int gcnt = 0;    // pairs recorded by previous group (uniform)

  for (int g = 2047; g >= 0; --g){
    const unsigned long long ball = __ballot(u_cur != 0u);
    if (ball != 0ULL){
      // replay previous group's death pairs (in order: handles chains)
      for (int k = 0; k < gcnt; ++k){
        const unsigned pr = gpair[k];
        root = (root == (pr >> 16)) ? (pr & 0xFFFFu) : root;
      }
      gcnt = 0;
      const int p3 = 4*g + 3;
#pragma unroll
      for (int t = 0; t < 4; ++t){
        if (((ball >> (16*t)) & 0xFFFFULL) == 0ULL) continue; // peak: par[p]=p stays
        const int p = p3 - t;
        const unsigned r_up = (unsigned)__builtin_amdgcn_readlane((int)root, 16*t);
        const bool cond = (u_cur != 0u) && ((lane >> 4) == t) && (root != r_up);
        unsigned long long dm = __ballot(cond);
        if (cond){ death[root] = (unsigned short)p; par[root] = (unsigned short)r_up; }
        if (lane == 16*t) par[p] = (unsigned short)r_up;   // attach p
        while (dm){
          const int b = (int)__ffsll((unsigned long long)dm) - 1;
          const unsigned d = (unsigned)__builtin_amdgcn_readlane((int)root, b);
          dm &= ~__ballot(cond && (root == d));            // dedupe this root
          if (lane == 0){ deadlist[nd] = (unsigned short)d; gpair[gcnt] = (d << 16) | r_up; }
          // keep par[d'] live for all previously-dead roots pointing at d
          for (int l = lane; l < nd; l += 64){
            const unsigned d2 = deadlist[l];
            if (par[d2] == (unsigned short)d) par[d2] = (unsigned short)r_up;
          }
          ++nd; ++gcnt;
          root = (root == d) ? r_up : root;                // register fixup
        }
        root = (u_cur == (unsigned)p) ? r_up : root;       // in-group attach fixup
      }
    } else {
      gcnt = 0;
    }
    // pipelined gathers: h2 for g-1 (post-this-group state), h1 for g-2
    const unsigned h2n = par[h1n];
    const unsigned u_n2 = q[0];
#pragma unroll
    for (int k = 0; k < 5; ++k) q[k] = q[k+1];
    q[5] = (g >= 8) ? (unsigned)ups_t[(size_t)(g-8)*64 + lane] : 0u;
    const unsigned h1n2 = par[u_n2];
    u_cur = u_n1; u_n1 = u_n2; root = h2n; h1n = h1n2;
  }
  __syncthreads();

  // ---- fused loss (bit-identical emulation of round-2 k_loss) ----
  float accv[16];
#pragma unroll
  for (int v2 = 0; v2 < 16; ++v2) accv[v2] = 0.f;
  for (int v2 = 0; v2 < 16; ++v2){
    const int t = lane + 64*v2;
    for (int e = t; e < NN; e += 1024){
      const int dr = death[e];
      if (dr != 0xFFFF) accv[v2] += dens[e] - dens[dr];
    }
  }
  for (int v2 = 0; v2 < 16; ++v2) psum[lane + 64*v2] = accv[v2];
  for (int o = 512; o; o >>= 1){
    for (int t = lane; t < o; t += 64) psum[t] += psum[t + o];
  }
  const float S = psum[0];
  unsigned long long sel10[10];
  unsigned long long last = ~0ULL;
#pragma unroll
  for (int t10 = 0; t10 < 10; ++t10){
    unsigned long long km = 0ULL;
    for (int e = lane; e < NN; e += 64){
      const int dr = death[e];
      if (dr != 0xFFFF){
        const float pers = dens[e] - dens[dr];
        const unsigned long long k = (((unsigned long long)__float_as_uint(pers)) << 13) | (unsigned)e;
        if (k < last && k > km) km = k;
      }
    }
#pragma unroll
    for (int off = 32; off; off >>= 1){
      const unsigned long long o =
        (((unsigned long long)(unsigned)__shfl_xor((int)(km >> 32), off)) << 32)
        | (unsigned long long)(unsigned)__shfl_xor((int)(km & 0xFFFFFFFFu), off);
      km = (o > km) ? o : km;
    }
    sel10[t10] = km;
    last = km;
  }
  if (lane == 0){
    float top = 0.f;
#pragma unroll
    for (int t10 = 0; t10 < 10; ++t10)
      if (sel10[t10]) top += __uint_as_float((unsigned)(sel10[t10] >> 13));
    float strong = 0.f, dest0 = 0.f, dest1 = 0.f;
    if (sel10[0]){
      const unsigned e0 = (unsigned)(sel10[0] & 8191ULL);
      dest0 = dens[e0]; dest1 = dens[death[e0]];
    }
#pragma unroll
    for (int t10 = 1; t10 < 10; ++t10){
      if (!sel10[t10]) continue;
      const unsigned e = (unsigned)(sel10[t10] & 8191ULL);
      const float a = dens[e] - dest0;
      const float b = dens[death[e]] - dest1;
      strong += sqrtf(a*a + b*b);
    }
    const float weak = (S - top) / 1.41421356237309515f;
    out[0] = weak + strong;
  }
}

// =====================================================================
// launch — 4 dispatches
// =====================================================================
extern "C" void kernel_launch(void* const* d_in, const int* in_sizes, int n_in,
                              void* d_out, int out_size, void* d_ws, size_t ws_size,
                              hipStream_t stream){
  const float* x = (const float*)d_in[0];
  char* w = (char*)d_ws;
  float*          sq     = (float*)(w + 0);        // 32KB
  float*          res    = (float*)(w + 32768);    // 32KB
  float*          dens_s = (float*)(w + 65536);    // 32KB
  unsigned short* nn16   = (unsigned short*)(w + 98304);   // 256KB
  unsigned short* ups_t  = (unsigned short*)(w + 360448);  // 256KB
  float*          xT     = (float*)(w + 622592);   // 2MB (optional)
  const int use_xt = (ws_size >= (size_t)(622592 + NN*DD*4)) ? 1 : 0;

  k_pre<<<128, 256, 0, stream>>>(x, xT, sq, use_xt);
  if (use_xt) k_cand<true ><<<1024, 256, 0, stream>>>(x, xT, sq, res, nn16);
  else        k_cand<false><<<1024, 256, 0, stream>>>(x, xT, sq, res, nn16);
  k_sortu<<<1, 1024, 0, stream>>>(res, nn16, dens_s, ups_t);
  k_uf<<<1, 64, 0, stream>>>(ups_t, dens_s, (float*)d_out);
}